// Round 1
// baseline (615.661 us; speedup 1.0000x reference)
//
#include <hip/hip_runtime.h>
#include <cstdint>

#define EMB_D 64

// Monotone float<->uint encoding so atomicMax(uint) == float max.
// All finite floats encode > 0, so memset-0 init acts as -inf sentinel.
__device__ __forceinline__ unsigned enc_f(float f) {
    unsigned u = __float_as_uint(f);
    return (u & 0x80000000u) ? ~u : (u | 0x80000000u);
}
__device__ __forceinline__ float dec_f(unsigned u) {
    return (u & 0x80000000u) ? __uint_as_float(u & 0x7FFFFFFFu)
                             : __uint_as_float(~u);
}

// K1: per-node projections. One 64-lane wave per node; shuffle-reduce.
__global__ void k_alpha(const float* __restrict__ h, const float* __restrict__ hq,
                        const float* __restrict__ W,
                        float* __restrict__ alpha_q, float* __restrict__ alpha_k,
                        int n_nodes) {
    int gid  = blockIdx.x * blockDim.x + threadIdx.x;
    int node = gid >> 6;
    int lane = gid & 63;
    if (node >= n_nodes) return;
    float vq = hq[(long long)node * EMB_D + lane] * W[lane];
    float vk = h [(long long)node * EMB_D + lane] * W[EMB_D + lane];
#pragma unroll
    for (int o = 32; o > 0; o >>= 1) {
        vq += __shfl_xor(vq, o, 64);
        vk += __shfl_xor(vk, o, 64);
    }
    if (lane == 0) { alpha_q[node] = vq; alpha_k[node] = vk; }
}

// K2: per-edge score + segment max (encoded atomicMax).
__global__ void k_score(const int* __restrict__ src, const int* __restrict__ dst,
                        const float* __restrict__ alpha_q, const float* __restrict__ alpha_k,
                        const float* __restrict__ b,
                        float* __restrict__ scores, unsigned* __restrict__ seg_max_u,
                        int n_edges) {
    int e = blockIdx.x * blockDim.x + threadIdx.x;
    if (e >= n_edges) return;
    int di = dst[e];
    float s = alpha_q[di] + alpha_k[src[e]] + b[0];
    scores[e] = s;
    atomicMax(&seg_max_u[di], enc_f(s));
}

// K3: per-edge exp(s - max) + segment sum.
__global__ void k_exp(const int* __restrict__ dst, const unsigned* __restrict__ seg_max_u,
                      float* __restrict__ scores, float* __restrict__ seg_sum,
                      int n_edges) {
    int e = blockIdx.x * blockDim.x + threadIdx.x;
    if (e >= n_edges) return;
    int di = dst[e];
    float ev = expf(scores[e] - dec_f(seg_max_u[di]));
    scores[e] = ev;
    atomicAdd(&seg_sum[di], ev);
}

// K4: one wave per edge, lane = feature dim. Coalesced row gather of h[src],
// coalesced atomicAdd into out[dst] row.
__global__ void k_scatter(const int* __restrict__ src, const int* __restrict__ dst,
                          const float* __restrict__ h, const float* __restrict__ scores,
                          const float* __restrict__ seg_sum, float* __restrict__ out,
                          int n_edges) {
    long long t = (long long)blockIdx.x * blockDim.x + threadIdx.x;
    int e = (int)(t >> 6);
    if (e >= n_edges) return;
    int d  = (int)(t & 63);
    int si = src[e];
    int di = dst[e];
    float a = scores[e] / (seg_sum[di] + 1e-16f);
    atomicAdd(&out[(long long)di * EMB_D + d], h[(long long)si * EMB_D + d] * a);
}

extern "C" void kernel_launch(void* const* d_in, const int* in_sizes, int n_in,
                              void* d_out, int out_size, void* d_ws, size_t ws_size,
                              hipStream_t stream) {
    const float* h  = (const float*)d_in[0];
    const float* hq = (const float*)d_in[1];
    const float* W  = (const float*)d_in[2];   // [2*D] (flattened [2D,1])
    const float* b  = (const float*)d_in[3];   // [1]
    const int*   ei = (const int*)d_in[4];     // [2, E] int32 per harness convention

    int n_nodes = in_sizes[0] / EMB_D;
    int n_edges = in_sizes[4] / 2;
    const int* src = ei;                // edge_index[0] = message source j
    const int* dst = ei + n_edges;      // edge_index[1] = aggregation index i

    float* out = (float*)d_out;

    // Workspace layout (floats): alpha_q[N] | alpha_k[N] | seg_sum[N] | seg_max_u[N] | scores[E]
    float*    ws_f      = (float*)d_ws;
    float*    alpha_q   = ws_f;
    float*    alpha_k   = ws_f + n_nodes;
    float*    seg_sum   = ws_f + 2LL * n_nodes;
    unsigned* seg_max_u = (unsigned*)(ws_f + 3LL * n_nodes);
    float*    scores    = ws_f + 4LL * n_nodes;

    // Harness poisons d_out / d_ws with 0xAA each call — zero what we accumulate into.
    hipMemsetAsync(out, 0, (size_t)out_size * sizeof(float), stream);
    hipMemsetAsync(seg_sum, 0, (size_t)2 * n_nodes * sizeof(float), stream); // seg_sum + seg_max_u

    {
        long long threads = (long long)n_nodes * 64;
        int blocks = (int)((threads + 255) / 256);
        k_alpha<<<blocks, 256, 0, stream>>>(h, hq, W, alpha_q, alpha_k, n_nodes);
    }
    {
        int blocks = (n_edges + 255) / 256;
        k_score<<<blocks, 256, 0, stream>>>(src, dst, alpha_q, alpha_k, b,
                                            scores, seg_max_u, n_edges);
        k_exp<<<blocks, 256, 0, stream>>>(dst, seg_max_u, scores, seg_sum, n_edges);
    }
    {
        long long threads = (long long)n_edges * 64;
        int blocks = (int)((threads + 255) / 256);
        k_scatter<<<blocks, 256, 0, stream>>>(src, dst, h, scores, seg_sum, out, n_edges);
    }
}

// Round 2
// 413.403 us; speedup vs baseline: 1.4893x; 1.4893x over previous
//
#include <hip/hip_runtime.h>
#include <cstdint>
#include <math.h>

#define EMB_D 64
#define SCAN_CHUNK 2048   // elements per scan1 block (256 thr x 8)

// ---------- K1: per-node projections (wave per node, shuffle reduce) ----------
__global__ void k_alpha(const float* __restrict__ h, const float* __restrict__ hq,
                        const float* __restrict__ W,
                        float* __restrict__ alpha_q, float* __restrict__ alpha_k,
                        int n_nodes) {
    int gid  = blockIdx.x * blockDim.x + threadIdx.x;
    int node = gid >> 6;
    int lane = gid & 63;
    if (node >= n_nodes) return;
    float vq = hq[(long long)node * EMB_D + lane] * W[lane];
    float vk = h [(long long)node * EMB_D + lane] * W[EMB_D + lane];
#pragma unroll
    for (int o = 32; o > 0; o >>= 1) {
        vq += __shfl_xor(vq, o, 64);
        vk += __shfl_xor(vk, o, 64);
    }
    if (lane == 0) { alpha_q[node] = vq; alpha_k[node] = vk; }
}

// ---------- K2: histogram of dst ----------
__global__ void k_hist(const int* __restrict__ dst, int* __restrict__ deg, int n_edges) {
    int e = blockIdx.x * blockDim.x + threadIdx.x;
    if (e >= n_edges) return;
    atomicAdd(&deg[dst[e]], 1);
}

// ---------- K3a: per-chunk exclusive scan (256 thr x 8 elem) ----------
__global__ void k_scan1(const int* __restrict__ deg, int* __restrict__ row_ptr,
                        int* __restrict__ chunk_aux, int n) {
    __shared__ int lds[256];
    int tid  = threadIdx.x;
    int base = blockIdx.x * SCAN_CHUNK + tid * 8;
    int v[8];
    int s = 0;
#pragma unroll
    for (int j = 0; j < 8; ++j) {
        int idx = base + j;
        v[j] = (idx < n) ? deg[idx] : 0;
        s += v[j];
    }
    lds[tid] = s;
    __syncthreads();
    for (int off = 1; off < 256; off <<= 1) {
        int t = (tid >= off) ? lds[tid - off] : 0;
        __syncthreads();
        lds[tid] += t;
        __syncthreads();
    }
    int excl = lds[tid] - s;
    if (tid == 255) chunk_aux[blockIdx.x] = lds[255];
    int run = excl;
#pragma unroll
    for (int j = 0; j < 8; ++j) {
        int idx = base + j;
        if (idx < n) row_ptr[idx] = run;
        run += v[j];
    }
}

// ---------- K3b: scan the chunk sums (single wave, in place) ----------
__global__ void k_scan2(int* __restrict__ chunk_aux, int n_chunks) {
    int lane = threadIdx.x & 63;
    int orig = (lane < n_chunks) ? chunk_aux[lane] : 0;
    int v = orig;
#pragma unroll
    for (int off = 1; off < 64; off <<= 1) {
        int t = __shfl_up(v, off, 64);
        if (lane >= off) v += t;
    }
    chunk_aux[lane] = v - orig;  // exclusive
}

// ---------- K3c: finalize row_ptr, init cursor ----------
__global__ void k_scan3(int* __restrict__ row_ptr, int* __restrict__ cursor,
                        const int* __restrict__ chunk_aux, int n, int n_edges) {
    int i = blockIdx.x * blockDim.x + threadIdx.x;
    if (i >= n) return;
    int rp = row_ptr[i] + chunk_aux[i / SCAN_CHUNK];
    row_ptr[i] = rp;
    cursor[i]  = rp;
    if (i == 0) row_ptr[n] = n_edges;
}

// ---------- K4: fill CSR buckets ----------
__global__ void k_fill(const int* __restrict__ src, const int* __restrict__ dst,
                       int* __restrict__ cursor, int* __restrict__ csr_src, int n_edges) {
    int e = blockIdx.x * blockDim.x + threadIdx.x;
    if (e >= n_edges) return;
    int pos = atomicAdd(&cursor[dst[e]], 1);
    csr_src[pos] = src[e];
}

// ---------- K5: fused softmax + weighted aggregate, wave per dst node ----------
__global__ void k_main(const int* __restrict__ row_ptr, const int* __restrict__ csr_src,
                       const float* __restrict__ alpha_q, const float* __restrict__ alpha_k,
                       const float* __restrict__ b, const float* __restrict__ h,
                       float* __restrict__ out, int n_nodes) {
    int gid  = blockIdx.x * blockDim.x + threadIdx.x;
    int node = gid >> 6;
    int lane = gid & 63;
    if (node >= n_nodes) return;
    int beg = row_ptr[node], end = row_ptr[node + 1];
    float aqb = alpha_q[node] + b[0];

    float m = -INFINITY, l = 0.f, acc = 0.f;
    for (int pos = beg; pos < end; pos += 64) {
        int cnt = end - pos; if (cnt > 64) cnt = 64;
        int   sj = 0;
        float s  = -INFINITY;
        if (lane < cnt) {
            sj = csr_src[pos + lane];          // coalesced
            s  = aqb + alpha_k[sj];            // parallel gather (L2-resident)
        }
        // wave max of chunk scores
        float mc = s;
#pragma unroll
        for (int o = 32; o > 0; o >>= 1) mc = fmaxf(mc, __shfl_xor(mc, o, 64));
        float mn    = fmaxf(m, mc);
        float scale = expf(m - mn);            // m=-inf first iter -> 0
        float p     = (lane < cnt) ? expf(s - mn) : 0.f;
        float ps = p;
#pragma unroll
        for (int o = 32; o > 0; o >>= 1) ps += __shfl_xor(ps, o, 64);
        l   = l * scale + ps;
        acc = acc * scale;
        for (int i = 0; i < cnt; ++i) {
            int   sjb = __shfl(sj, i, 64);
            float pb  = __shfl(p,  i, 64);
            acc = fmaf(pb, h[(long long)sjb * EMB_D + lane], acc);
        }
        m = mn;
    }
    out[(long long)node * EMB_D + lane] = acc / (l + 1e-16f);
}

extern "C" void kernel_launch(void* const* d_in, const int* in_sizes, int n_in,
                              void* d_out, int out_size, void* d_ws, size_t ws_size,
                              hipStream_t stream) {
    const float* h  = (const float*)d_in[0];
    const float* hq = (const float*)d_in[1];
    const float* W  = (const float*)d_in[2];   // [2*D]
    const float* b  = (const float*)d_in[3];   // [1]
    const int*   ei = (const int*)d_in[4];     // [2, E] int32

    int n_nodes = in_sizes[0] / EMB_D;
    int n_edges = in_sizes[4] / 2;
    const int* src = ei;
    const int* dst = ei + n_edges;
    float* out = (float*)d_out;

    // Workspace layout (4 B elems): alpha_q[N] | alpha_k[N] | deg/cursor[N] |
    //   row_ptr[N+1] | chunk_aux[64] | csr_src[E]   (~8.0 MB)
    float* alpha_q  = (float*)d_ws;
    float* alpha_k  = alpha_q + n_nodes;
    int*   cursor   = (int*)(alpha_k + n_nodes);     // deg during build, cursor after
    int*   row_ptr  = cursor + n_nodes;
    int*   chunkaux = row_ptr + (n_nodes + 1);
    int*   csr_src  = chunkaux + 64;

    int n_chunks = (n_nodes + SCAN_CHUNK - 1) / SCAN_CHUNK;

    // zero the degree histogram (ws is poisoned with 0xAA each call)
    hipMemsetAsync(cursor, 0, (size_t)n_nodes * sizeof(int), stream);

    {   // projections (independent of CSR build)
        long long threads = (long long)n_nodes * 64;
        k_alpha<<<(int)((threads + 255) / 256), 256, 0, stream>>>(h, hq, W, alpha_q, alpha_k, n_nodes);
    }
    {   // CSR build
        int eb = (n_edges + 255) / 256;
        k_hist <<<eb, 256, 0, stream>>>(dst, cursor, n_edges);
        k_scan1<<<n_chunks, 256, 0, stream>>>(cursor, row_ptr, chunkaux, n_nodes);
        k_scan2<<<1, 64, 0, stream>>>(chunkaux, n_chunks);
        k_scan3<<<(n_nodes + 255) / 256, 256, 0, stream>>>(row_ptr, cursor, chunkaux, n_nodes, n_edges);
        k_fill <<<eb, 256, 0, stream>>>(src, dst, cursor, csr_src, n_edges);
    }
    {   // fused softmax + aggregate
        long long threads = (long long)n_nodes * 64;
        k_main<<<(int)((threads + 255) / 256), 256, 0, stream>>>(row_ptr, csr_src, alpha_q, alpha_k,
                                                                 b, h, out, n_nodes);
    }
}